// Round 5
// baseline (330.274 us; speedup 1.0000x reference)
//
#include <hip/hip_runtime.h>
#include <hip/hip_bf16.h>

namespace {

constexpr int T_STEPS = 256;
constexpr int HD = 50;   // hidden size
constexpr int HP = 64;   // padded hidden
constexpr int KST = 72;  // LDS row stride in bf16 elems
constexpr int BT = 16;   // batch tile per block
constexpr int NW = 6;    // waves: (layer, M-half) — halves B-operand replication vs R1/R3
constexpr int NTHR = NW * 64;  // 384
constexpr int XST = 34;  // xls row stride in floats

typedef __attribute__((ext_vector_type(8))) short bf16x8;
typedef __attribute__((ext_vector_type(4))) float f32x4;

__device__ __forceinline__ unsigned short f2bf(float x) {
  __hip_bfloat16 h = __float2bfloat16(x);
  return *reinterpret_cast<unsigned short*>(&h);
}
__device__ __forceinline__ float bf2f(unsigned short u) {
  __hip_bfloat16 h;
  *reinterpret_cast<unsigned short*>(&h) = u;
  return __bfloat162float(h);
}
__device__ __forceinline__ float fast_tanh(float x) {
  float e = __expf(2.0f * x);
  return 1.0f - 2.0f * __builtin_amdgcn_rcpf(e + 1.0f);
}

#define MFMA __builtin_amdgcn_mfma_f32_16x16x32_bf16

// full hi/lo product (Ah·bhi + Ah·blo + Al·bhi) split into 2 independent 3-deep chains
__device__ __forceinline__ void mm6(f32x4& c1, f32x4& c2, const bf16x8 Ah[2],
                                    const bf16x8 Al[2], const bf16x8 b[2][2]) {
  c1 = MFMA(Ah[0], b[0][0], c1, 0, 0, 0);
  c2 = MFMA(Ah[1], b[1][1], c2, 0, 0, 0);
  c1 = MFMA(Ah[1], b[1][0], c1, 0, 0, 0);
  c2 = MFMA(Al[0], b[0][0], c2, 0, 0, 0);
  c1 = MFMA(Ah[0], b[0][1], c1, 0, 0, 0);
  c2 = MFMA(Al[1], b[1][0], c2, 0, 0, 0);
}

// Orientation: D[i][b] = sum_k W[i][k] * h[b][k]; A = weights in VGPRs, B = h from LDS.
// Waves = (layer, M-half): wave order [L0,L1,L2,L2,L1,L0] balances MFMA across SIMDs
// under round-robin wave->SIMD placement (36/36/24/24 per iter).
// Diagonal offsets 0/2/4 + 3-slot ring (R3): cross-layer B-frags register-prefetched.
__global__ __launch_bounds__(NTHR, 1) void rnn3_kernel(
    const float* __restrict__ x,
    const float* __restrict__ Wih1, const float* __restrict__ Whh1,
    const float* __restrict__ bih1, const float* __restrict__ bhh1,
    const float* __restrict__ Wih2, const float* __restrict__ Whh2,
    const float* __restrict__ bih2, const float* __restrict__ bhh2,
    const float* __restrict__ Wih3, const float* __restrict__ Whh3,
    const float* __restrict__ bih3, const float* __restrict__ bhh3,
    const float* __restrict__ fcw, const float* __restrict__ fcb,
    float* __restrict__ out) {
  __shared__ unsigned short hbuf[3][3][2][BT * KST];  // [ring][layer][hi/lo][b*KST+k]
  __shared__ float xls[T_STEPS][XST];                 // staged x
  __shared__ unsigned short scr[2][HP * KST];         // weight staging

  const int tid = threadIdx.x;
  const int w = tid >> 6;
  constexpr int wLtab[6] = {0, 1, 2, 2, 1, 0};
  constexpr int wHtab[6] = {0, 0, 0, 1, 1, 1};
  const int myL = wLtab[w];
  const int myH = wHtab[w];        // M-half: i in [32*myH, 32*myH+32)
  const int lane = tid & 63;
  const int quad = lane >> 4;
  const int l15 = lane & 15;
  const int b0 = blockIdx.x * BT;

  // zero all 3 ring slots (initial h=0 and the k>=HD pad)
  {
    unsigned int* hz = reinterpret_cast<unsigned int*>(&hbuf[0][0][0][0]);
    const int n = 3 * 3 * 2 * BT * KST / 2;
    for (int i = tid; i < n; i += NTHR) hz[i] = 0u;
  }
  // stage x -> LDS
  for (int idx = tid; idx < BT * T_STEPS; idx += NTHR) {
    int b = idx >> 8, t = idx & 255;
    float2 v = *reinterpret_cast<const float2*>(x + (size_t)(b0 + b) * (T_STEPS * 2) + 2 * t);
    xls[t][2 * b] = v.x;
    xls[t][2 * b + 1] = v.y;
  }

  // ---- stage the five 50x50 matrices, split fp32 -> bf16 hi/lo ----
  const float* mats[5] = {Whh1, Wih2, Whh2, Wih3, Whh3};
  constexpr int matL[5] = {0, 1, 1, 2, 2};
  constexpr int matS[5] = {0, 0, 1, 0, 1};  // slot0 = cross (self for L0), slot1 = self
  bf16x8 wAh[2][2][2], wAl[2][2][2];  // [slot][tt][ks]
#pragma unroll
  for (int sl = 0; sl < 2; ++sl)
#pragma unroll
    for (int tt = 0; tt < 2; ++tt)
#pragma unroll
      for (int ks = 0; ks < 2; ++ks) { wAh[sl][tt][ks] = bf16x8(0); wAl[sl][tt][ks] = bf16x8(0); }

#pragma unroll
  for (int m = 0; m < 5; ++m) {
    __syncthreads();
    const float* W = mats[m];
    for (int idx = tid; idx < HP * HP; idx += NTHR) {
      int i = idx >> 6, k = idx & 63;
      float v = (i < HD && k < HD) ? W[i * HD + k] : 0.0f;
      unsigned short hi = f2bf(v);
      scr[0][i * KST + k] = hi;
      scr[1][i * KST + k] = f2bf(v - bf2f(hi));
    }
    __syncthreads();
    if (myL == matL[m]) {
      const int sl = matS[m];
#pragma unroll
      for (int tt = 0; tt < 2; ++tt) {
        const int arow = 16 * (2 * myH + tt) + l15;
#pragma unroll
        for (int ks = 0; ks < 2; ++ks) {
          wAh[sl][tt][ks] = *reinterpret_cast<const bf16x8*>(&scr[0][arow * KST + 32 * ks + 8 * quad]);
          wAl[sl][tt][ks] = *reinterpret_cast<const bf16x8*>(&scr[1][arow * KST + 32 * ks + 8 * quad]);
        }
      }
    }
  }

  // per-lane C-row constants, per tile
  const float* bi = (myL == 0) ? bih1 : (myL == 1) ? bih2 : bih3;
  const float* bh = (myL == 0) ? bhh1 : (myL == 1) ? bhh2 : bhh3;
  float wx0[2][4], wx1[2][4], bs[2][4];
#pragma unroll
  for (int tt = 0; tt < 2; ++tt)
#pragma unroll
    for (int r = 0; r < 4; ++r) {
      int i = 32 * myH + 16 * tt + 4 * quad + r;
      bool v = i < HD;
      bs[tt][r] = v ? (bi[i] + bh[i]) : 0.0f;
      wx0[tt][r] = (v && myL == 0) ? Wih1[i * 2 + 0] : 0.0f;
      wx1[tt][r] = (v && myL == 0) ? Wih1[i * 2 + 1] : 0.0f;
    }

  const int selfBuf = myL;
  const int crossBuf = (myL > 0) ? myL - 1 : 0;
  const int ldsOff = l15 * KST + 8 * quad;

  bf16x8 pfC[2][2];  // cross-layer B-frags for the CURRENT iter (loaded last iter)
#pragma unroll
  for (int ks = 0; ks < 2; ++ks)
#pragma unroll
    for (int h = 0; h < 2; ++h) pfC[ks][h] = bf16x8(0);

  __syncthreads();

  // ---- main loop: iter s computes h1_s, h2_{s-2}, h3_{s-4} ----
  for (int s = 0; s < T_STEPS + 4; ++s) {
    const int wr = s % 3;        // write slot
    const int rd = (s + 2) % 3;  // slot written at s-1

    const bool act = (myL == 0) ? (s < T_STEPS)
                   : (myL == 1) ? (s >= 2 && s < T_STEPS + 2)
                                : (s >= 4);

    // self-recurrent frags (written by sibling waves at s-1): post-barrier
    bf16x8 bS[2][2];
    if (act) {
#pragma unroll
      for (int ks = 0; ks < 2; ++ks)
#pragma unroll
        for (int h = 0; h < 2; ++h)
          bS[ks][h] = *reinterpret_cast<const bf16x8*>(
              &hbuf[rd][selfBuf][h][ldsOff + 32 * ks]);
    }
    // prefetch cross frags for NEXT iter (slot rd, written s-1; writers use wr != rd)
    bf16x8 pfN[2][2];
    if (myL > 0) {
#pragma unroll
      for (int ks = 0; ks < 2; ++ks)
#pragma unroll
        for (int h = 0; h < 2; ++h)
          pfN[ks][h] = *reinterpret_cast<const bf16x8*>(
              &hbuf[rd][crossBuf][h][ldsOff + 32 * ks]);
    }

    if (act) {
      f32x4 acc[2];
      if (myL == 0) {
        float2 xc = *reinterpret_cast<const float2*>(&xls[s][2 * l15]);
#pragma unroll
        for (int tt = 0; tt < 2; ++tt) {
          f32x4 c1, c2;
#pragma unroll
          for (int r = 0; r < 4; ++r) {
            c1[r] = bs[tt][r] + wx0[tt][r] * xc.x + wx1[tt][r] * xc.y;
            c2[r] = 0.0f;
          }
          mm6(c1, c2, wAh[0][tt], wAl[0][tt], bS);  // self (Whh1)
#pragma unroll
          for (int r = 0; r < 4; ++r) acc[tt][r] = c1[r] + c2[r];
        }
      } else {
#pragma unroll
        for (int tt = 0; tt < 2; ++tt) {
          f32x4 c1, c2, s1, s2;
#pragma unroll
          for (int r = 0; r < 4; ++r) { c1[r] = bs[tt][r]; c2[r] = 0.0f; s1[r] = 0.0f; s2[r] = 0.0f; }
          mm6(c1, c2, wAh[0][tt], wAl[0][tt], pfC);  // cross (Wih), prefetched operands
          mm6(s1, s2, wAh[1][tt], wAl[1][tt], bS);   // self (Whh)
#pragma unroll
          for (int r = 0; r < 4; ++r) acc[tt][r] = (c1[r] + c2[r]) + (s1[r] + s2[r]);
        }
      }

      // tanh -> bf16 hi/lo -> packed 8B writes
#pragma unroll
      for (int tt = 0; tt < 2; ++tt) {
        unsigned short hi[4], lo[4];
#pragma unroll
        for (int r = 0; r < 4; ++r) {
          float h = fast_tanh(acc[tt][r]);
          hi[r] = f2bf(h);
          lo[r] = f2bf(h - bf2f(hi[r]));
        }
        unsigned int h01 = (unsigned int)hi[0] | ((unsigned int)hi[1] << 16);
        unsigned int h23 = (unsigned int)hi[2] | ((unsigned int)hi[3] << 16);
        unsigned int l01 = (unsigned int)lo[0] | ((unsigned int)lo[1] << 16);
        unsigned int l23 = (unsigned int)lo[2] | ((unsigned int)lo[3] << 16);
        const int ic = 32 * myH + 16 * tt + 4 * quad;
        *reinterpret_cast<uint2*>(&hbuf[wr][myL][0][l15 * KST + ic]) = make_uint2(h01, h23);
        *reinterpret_cast<uint2*>(&hbuf[wr][myL][1][l15 * KST + ic]) = make_uint2(l01, l23);
      }
    }

    if (myL > 0) {
#pragma unroll
      for (int ks = 0; ks < 2; ++ks)
#pragma unroll
        for (int h = 0; h < 2; ++h) pfC[ks][h] = pfN[ks][h];
    }

    __syncthreads();
  }

  // ---- fc epilogue: h3_255 written at s=259 -> slot 259%3 = 1 ----
  if (tid < BT * 2) {
    int b = tid >> 1, o = tid & 1;
    const unsigned short* h3h = &hbuf[1][2][0][b * KST];
    const unsigned short* h3l = &hbuf[1][2][1][b * KST];
    float acc = fcb[o];
    for (int i = 0; i < HD; ++i)
      acc += fcw[o * HD + i] * (bf2f(h3h[i]) + bf2f(h3l[i]));
    out[(size_t)(b0 + b) * 2 + o] = acc;
  }
}

}  // namespace

extern "C" void kernel_launch(void* const* d_in, const int* in_sizes, int n_in,
                              void* d_out, int out_size, void* d_ws, size_t ws_size,
                              hipStream_t stream) {
  const float* x = (const float*)d_in[0];
  const float* Wih1 = (const float*)d_in[1];
  const float* Whh1 = (const float*)d_in[2];
  const float* bih1 = (const float*)d_in[3];
  const float* bhh1 = (const float*)d_in[4];
  const float* Wih2 = (const float*)d_in[5];
  const float* Whh2 = (const float*)d_in[6];
  const float* bih2 = (const float*)d_in[7];
  const float* bhh2 = (const float*)d_in[8];
  const float* Wih3 = (const float*)d_in[9];
  const float* Whh3 = (const float*)d_in[10];
  const float* bih3 = (const float*)d_in[11];
  const float* bhh3 = (const float*)d_in[12];
  const float* fcw = (const float*)d_in[13];
  const float* fcb = (const float*)d_in[14];

  rnn3_kernel<<<4096 / BT, NTHR, 0, stream>>>(x, Wih1, Whh1, bih1, bhh1,
                                              Wih2, Whh2, bih2, bhh2,
                                              Wih3, Whh3, bih3, bhh3,
                                              fcw, fcb, (float*)d_out);
}

// Round 6
// 252.917 us; speedup vs baseline: 1.3059x; 1.3059x over previous
//
#include <hip/hip_runtime.h>
#include <hip/hip_bf16.h>
#include <hip/hip_fp16.h>

namespace {

constexpr int T_STEPS = 256;
constexpr int HD = 50;    // hidden size
constexpr int HP = 64;    // padded hidden
constexpr int KST = 88;   // h-buf row stride in fp16 elems: 44 dwords ≡ 12 mod 32 -> uniform 2-way banks (free)
constexpr int KSTS = 72;  // weight staging stride
constexpr int BT = 16;    // batch tile per block
constexpr int NW = 12;    // waves: (layer, M-tile) — measured-best wave count
constexpr int NTHR = NW * 64;  // 768
constexpr int XST = 34;   // xls row stride in floats

typedef __attribute__((ext_vector_type(8))) _Float16 f16x8;
typedef __attribute__((ext_vector_type(4))) float f32x4;

__device__ __forceinline__ unsigned short f2h(float x) {
  __half h = __float2half(x);  // v_cvt_f16_f32, RNE
  return *reinterpret_cast<unsigned short*>(&h);
}
__device__ __forceinline__ float h2f(unsigned short u) {
  __half h;
  *reinterpret_cast<unsigned short*>(&h) = u;
  return __half2float(h);
}
__device__ __forceinline__ float fast_tanh(float x) {
  float e = __expf(2.0f * x);
  return 1.0f - 2.0f * __builtin_amdgcn_rcpf(e + 1.0f);
}

#define MFMA16 __builtin_amdgcn_mfma_f32_16x16x32_f16

// Orientation: D[i][b] = sum_k W[i][k] * h[b][k]
//   A = weights, static in VGPRs; B = h (single fp16) from LDS.
// W split: Wh = fp16(W); Wls = fp16((W - Wh) * 2048)  [scaled to dodge fp16 denormals]
//   D = (Wh·b) + (Wls·b) * 2^-11  — captures W to ~2^-22, h to 2^-11.
// Diagonal offsets 0/2/4, 3-slot ring, cross-layer register prefetch (R3 structure).
__global__ __launch_bounds__(NTHR, 3) void rnn3_kernel(
    const float* __restrict__ x,
    const float* __restrict__ Wih1, const float* __restrict__ Whh1,
    const float* __restrict__ bih1, const float* __restrict__ bhh1,
    const float* __restrict__ Wih2, const float* __restrict__ Whh2,
    const float* __restrict__ bih2, const float* __restrict__ bhh2,
    const float* __restrict__ Wih3, const float* __restrict__ Whh3,
    const float* __restrict__ bih3, const float* __restrict__ bhh3,
    const float* __restrict__ fcw, const float* __restrict__ fcb,
    float* __restrict__ out) {
  __shared__ unsigned short hbuf[3][3][BT * KST];  // [ring][layer][b*KST+k], fp16 bits
  __shared__ float xls[T_STEPS][XST];              // staged x
  __shared__ unsigned short scr[2][HP * KSTS];     // weight staging (hi / scaled-lo)

  const int tid = threadIdx.x;
  const int w = tid >> 6;
  const int myL = w >> 2;        // layer 0..2
  const int wv = w & 3;          // M-tile
  const int lane = tid & 63;
  const int quad = lane >> 4;
  const int l15 = lane & 15;
  const int b0 = blockIdx.x * BT;

  // zero all 3 ring slots (initial h=0 and the k>=HD pad)
  {
    unsigned int* hz = reinterpret_cast<unsigned int*>(&hbuf[0][0][0]);
    const int n = 3 * 3 * BT * KST / 2;
    for (int i = tid; i < n; i += NTHR) hz[i] = 0u;
  }
  // stage x -> LDS
  for (int idx = tid; idx < BT * T_STEPS; idx += NTHR) {
    int b = idx >> 8, t = idx & 255;
    float2 v = *reinterpret_cast<const float2*>(x + (size_t)(b0 + b) * (T_STEPS * 2) + 2 * t);
    xls[t][2 * b] = v.x;
    xls[t][2 * b + 1] = v.y;
  }

  // ---- stage the five 50x50 matrices: fp16 hi + scaled fp16 lo ----
  const float* mats[5] = {Whh1, Wih2, Whh2, Wih3, Whh3};
  constexpr int matL[5] = {0, 1, 1, 2, 2};
  constexpr int matS[5] = {0, 0, 1, 0, 1};  // slot0 = cross (self for L0), slot1 = self
  f16x8 wAh[2][2], wAl[2][2];  // [slot][kstep]
#pragma unroll
  for (int sl = 0; sl < 2; ++sl)
#pragma unroll
    for (int ks = 0; ks < 2; ++ks) { wAh[sl][ks] = f16x8(0); wAl[sl][ks] = f16x8(0); }

  const int arow = 16 * wv + l15;
#pragma unroll
  for (int m = 0; m < 5; ++m) {
    __syncthreads();
    const float* W = mats[m];
    for (int idx = tid; idx < HP * HP; idx += NTHR) {
      int i = idx >> 6, k = idx & 63;
      float v = (i < HD && k < HD) ? W[i * HD + k] : 0.0f;
      unsigned short hi = f2h(v);
      scr[0][i * KSTS + k] = hi;
      scr[1][i * KSTS + k] = f2h((v - h2f(hi)) * 2048.0f);  // scaled residual, fp16-normal range
    }
    __syncthreads();
    if (myL == matL[m]) {
      const int sl = matS[m];
      const unsigned short* ph = &scr[0][arow * KSTS + 8 * quad];
      const unsigned short* pl = &scr[1][arow * KSTS + 8 * quad];
      wAh[sl][0] = *reinterpret_cast<const f16x8*>(ph);
      wAh[sl][1] = *reinterpret_cast<const f16x8*>(ph + 32);
      wAl[sl][0] = *reinterpret_cast<const f16x8*>(pl);
      wAl[sl][1] = *reinterpret_cast<const f16x8*>(pl + 32);
    }
  }

  // per-lane C-row constants
  const int ic = 16 * wv + 4 * quad;
  const float* bi = (myL == 0) ? bih1 : (myL == 1) ? bih2 : bih3;
  const float* bh = (myL == 0) ? bhh1 : (myL == 1) ? bhh2 : bhh3;
  float wx0[4], wx1[4], bs[4];
#pragma unroll
  for (int r = 0; r < 4; ++r) {
    int i = ic + r;
    bool v = i < HD;
    bs[r] = v ? (bi[i] + bh[i]) : 0.0f;
    wx0[r] = (v && myL == 0) ? Wih1[i * 2 + 0] : 0.0f;
    wx1[r] = (v && myL == 0) ? Wih1[i * 2 + 1] : 0.0f;
  }

  const int selfBuf = myL;
  const int crossBuf = (myL > 0) ? myL - 1 : 0;
  const int ldsOff = l15 * KST + 8 * quad;
  constexpr float INV = 4.8828125e-4f;  // 2^-11

  f16x8 pfC[2];  // cross-layer B-frags for the CURRENT iter (loaded last iter)
  pfC[0] = f16x8(0);
  pfC[1] = f16x8(0);

  __syncthreads();

  // ---- main loop: iter s computes h1_s, h2_{s-2}, h3_{s-4} ----
  for (int s = 0; s < T_STEPS + 4; ++s) {
    const int wr = s % 3;        // write slot
    const int rd = (s + 2) % 3;  // slot written at s-1

    const bool act = (myL == 0) ? (s < T_STEPS)
                   : (myL == 1) ? (s >= 2 && s < T_STEPS + 2)
                                : (s >= 4);

    // self-recurrent frags (written by sibling waves at s-1): post-barrier
    f16x8 bS[2];
    if (act) {
#pragma unroll
      for (int ks = 0; ks < 2; ++ks)
        bS[ks] = *reinterpret_cast<const f16x8*>(&hbuf[rd][selfBuf][ldsOff + 32 * ks]);
    }
    // prefetch cross frags for NEXT iter (slot rd, written s-1; writers use wr != rd)
    f16x8 pfN[2];
    if (myL > 0) {
#pragma unroll
      for (int ks = 0; ks < 2; ++ks)
        pfN[ks] = *reinterpret_cast<const f16x8*>(&hbuf[rd][crossBuf][ldsOff + 32 * ks]);
    }

    if (act) {
      f32x4 acc;
      if (myL == 0) {
        float2 xc = *reinterpret_cast<const float2*>(&xls[s][2 * l15]);
        f32x4 c1, c2;
#pragma unroll
        for (int r = 0; r < 4; ++r) {
          c1[r] = bs[r] + wx0[r] * xc.x + wx1[r] * xc.y;
          c2[r] = 0.0f;
        }
        // two independent 2-deep chains
        c1 = MFMA16(wAh[0][0], bS[0], c1, 0, 0, 0);
        c2 = MFMA16(wAl[0][0], bS[0], c2, 0, 0, 0);
        c1 = MFMA16(wAh[0][1], bS[1], c1, 0, 0, 0);
        c2 = MFMA16(wAl[0][1], bS[1], c2, 0, 0, 0);
#pragma unroll
        for (int r = 0; r < 4; ++r) acc[r] = c1[r] + c2[r] * INV;
      } else {
        f32x4 c1, c2, s1, s2;
#pragma unroll
        for (int r = 0; r < 4; ++r) { c1[r] = bs[r]; c2[r] = 0.0f; s1[r] = 0.0f; s2[r] = 0.0f; }
        // four independent 2-deep chains; cross uses prefetched operands
        c1 = MFMA16(wAh[0][0], pfC[0], c1, 0, 0, 0);
        c2 = MFMA16(wAl[0][0], pfC[0], c2, 0, 0, 0);
        s1 = MFMA16(wAh[1][0], bS[0], s1, 0, 0, 0);
        s2 = MFMA16(wAl[1][0], bS[0], s2, 0, 0, 0);
        c1 = MFMA16(wAh[0][1], pfC[1], c1, 0, 0, 0);
        c2 = MFMA16(wAl[0][1], pfC[1], c2, 0, 0, 0);
        s1 = MFMA16(wAh[1][1], bS[1], s1, 0, 0, 0);
        s2 = MFMA16(wAl[1][1], bS[1], s2, 0, 0, 0);
#pragma unroll
        for (int r = 0; r < 4; ++r) acc[r] = (c1[r] + s1[r]) + (c2[r] + s2[r]) * INV;
      }

      // tanh -> single fp16 -> one packed 8B write per wave
      unsigned short ht[4];
#pragma unroll
      for (int r = 0; r < 4; ++r) ht[r] = f2h(fast_tanh(acc[r]));
      unsigned int h01 = (unsigned int)ht[0] | ((unsigned int)ht[1] << 16);
      unsigned int h23 = (unsigned int)ht[2] | ((unsigned int)ht[3] << 16);
      *reinterpret_cast<uint2*>(&hbuf[wr][myL][l15 * KST + ic]) = make_uint2(h01, h23);
    }

    if (myL > 0) {
      pfC[0] = pfN[0];
      pfC[1] = pfN[1];
    }

    __syncthreads();
  }

  // ---- fc epilogue: h3_255 written at s=259 -> slot 259%3 = 1 ----
  if (tid < BT * 2) {
    int b = tid >> 1, o = tid & 1;
    const unsigned short* h3 = &hbuf[1][2][b * KST];
    float acc = fcb[o];
    for (int i = 0; i < HD; ++i) acc += fcw[o * HD + i] * h2f(h3[i]);
    out[(size_t)(b0 + b) * 2 + o] = acc;
  }
}

}  // namespace

extern "C" void kernel_launch(void* const* d_in, const int* in_sizes, int n_in,
                              void* d_out, int out_size, void* d_ws, size_t ws_size,
                              hipStream_t stream) {
  const float* x = (const float*)d_in[0];
  const float* Wih1 = (const float*)d_in[1];
  const float* Whh1 = (const float*)d_in[2];
  const float* bih1 = (const float*)d_in[3];
  const float* bhh1 = (const float*)d_in[4];
  const float* Wih2 = (const float*)d_in[5];
  const float* Whh2 = (const float*)d_in[6];
  const float* bih2 = (const float*)d_in[7];
  const float* bhh2 = (const float*)d_in[8];
  const float* Wih3 = (const float*)d_in[9];
  const float* Whh3 = (const float*)d_in[10];
  const float* bih3 = (const float*)d_in[11];
  const float* bhh3 = (const float*)d_in[12];
  const float* fcw = (const float*)d_in[13];
  const float* fcb = (const float*)d_in[14];

  rnn3_kernel<<<4096 / BT, NTHR, 0, stream>>>(x, Wih1, Whh1, bih1, bhh1,
                                              Wih2, Whh2, bih2, bhh2,
                                              Wih3, Whh3, bih3, bhh3,
                                              fcw, fcb, (float*)d_out);
}

// Round 7
// 201.706 us; speedup vs baseline: 1.6374x; 1.2539x over previous
//
#include <hip/hip_runtime.h>
#include <hip/hip_fp16.h>

namespace {

constexpr int T_STEPS = 256;
constexpr int HD = 50;    // hidden size
constexpr int HP = 64;    // padded hidden
constexpr int KST = 88;   // h-buf row stride in fp16 elems (44 dwords ≡ 12 mod 32 -> cheap banks)
constexpr int KSTS = 72;  // weight staging stride
constexpr int BT = 16;    // batch tile per block
constexpr int NTHR = 768; // 12 waves: (layer, M-tile) — measured-best config (R5)
constexpr int XST = 34;   // xls row stride in floats
constexpr int LAY_SH = BT * KST;     // shorts per (slot, layer)
constexpr int SLOT_SH = 3 * LAY_SH;  // shorts per ring slot

typedef __attribute__((ext_vector_type(8))) _Float16 f16x8;
typedef __attribute__((ext_vector_type(4))) float f32x4;

__device__ __forceinline__ unsigned short f2h(float x) {
  __half h = __float2half(x);  // v_cvt_f16_f32, RNE — keep RNE for absmax margin
  return *reinterpret_cast<unsigned short*>(&h);
}
__device__ __forceinline__ float h2f(unsigned short u) {
  __half h;
  *reinterpret_cast<unsigned short*>(&h) = u;
  return __half2float(h);
}
__device__ __forceinline__ float fast_tanh(float x) {
  float e = __expf(2.0f * x);
  return 1.0f - 2.0f * __builtin_amdgcn_rcpf(e + 1.0f);
}

#define MFMA16 __builtin_amdgcn_mfma_f32_16x16x32_f16

// Orientation: D[i][b] = sum_k W[i][k] * h[b][k]
//   A = weights static in VGPRs; B = h (single fp16) from LDS.
// W split: Wh = fp16(W); Wl = fp16((W - Wh) * 2048)  -> D = Wh·b + (Wl·b)·2^-11.
// Diagonal offsets 0/2/4, 3-slot ring, cross-layer register prefetch.
// Steady state (s=4..255) unrolled by 3 with LITERAL ring slots: LDS addresses
// fold to ds-instruction immediates, pf copies vanish in SSA — attacks the
// R5 VALU overhead (47% VALUBusy >> useful work).
__global__ __launch_bounds__(NTHR, 3) void rnn3_kernel(
    const float* __restrict__ x,
    const float* __restrict__ Wih1, const float* __restrict__ Whh1,
    const float* __restrict__ bih1, const float* __restrict__ bhh1,
    const float* __restrict__ Wih2, const float* __restrict__ Whh2,
    const float* __restrict__ bih2, const float* __restrict__ bhh2,
    const float* __restrict__ Wih3, const float* __restrict__ Whh3,
    const float* __restrict__ bih3, const float* __restrict__ bhh3,
    const float* __restrict__ fcw, const float* __restrict__ fcb,
    float* __restrict__ out) {
  __shared__ unsigned short hbuf[3 * SLOT_SH];  // [ring][layer][b*KST+k], fp16 bits
  __shared__ float xls[T_STEPS][XST];           // staged x
  __shared__ unsigned short scr[2][HP * KSTS];  // weight staging (hi / scaled-lo)

  const int tid = threadIdx.x;
  const int w = tid >> 6;
  const int myL = w >> 2;        // layer 0..2
  const int wv = w & 3;          // M-tile
  const int lane = tid & 63;
  const int quad = lane >> 4;
  const int l15 = lane & 15;
  const int b0 = blockIdx.x * BT;

  // zero all 3 ring slots (initial h=0 and the k>=HD pad)
  {
    unsigned int* hz = reinterpret_cast<unsigned int*>(hbuf);
    const int n = 3 * SLOT_SH / 2;
    for (int i = tid; i < n; i += NTHR) hz[i] = 0u;
  }
  // stage x -> LDS
  for (int idx = tid; idx < BT * T_STEPS; idx += NTHR) {
    int b = idx >> 8, t = idx & 255;
    float2 v = *reinterpret_cast<const float2*>(x + (size_t)(b0 + b) * (T_STEPS * 2) + 2 * t);
    xls[t][2 * b] = v.x;
    xls[t][2 * b + 1] = v.y;
  }

  // ---- stage the five 50x50 matrices: fp16 hi + scaled fp16 lo ----
  const float* mats[5] = {Whh1, Wih2, Whh2, Wih3, Whh3};
  constexpr int matL[5] = {0, 1, 1, 2, 2};
  constexpr int matS[5] = {0, 0, 1, 0, 1};  // slot0 = cross (self for L0), slot1 = self
  f16x8 wAh[2][2], wAl[2][2];  // [slot][kstep]
#pragma unroll
  for (int sl = 0; sl < 2; ++sl)
#pragma unroll
    for (int ks = 0; ks < 2; ++ks) { wAh[sl][ks] = f16x8(0); wAl[sl][ks] = f16x8(0); }

  const int arow = 16 * wv + l15;
#pragma unroll
  for (int m = 0; m < 5; ++m) {
    __syncthreads();
    const float* W = mats[m];
    for (int idx = tid; idx < HP * HP; idx += NTHR) {
      int i = idx >> 6, k = idx & 63;
      float v = (i < HD && k < HD) ? W[i * HD + k] : 0.0f;
      unsigned short hi = f2h(v);
      scr[0][i * KSTS + k] = hi;
      scr[1][i * KSTS + k] = f2h((v - h2f(hi)) * 2048.0f);  // scaled residual
    }
    __syncthreads();
    if (myL == matL[m]) {
      const int sl = matS[m];
      const unsigned short* ph = &scr[0][arow * KSTS + 8 * quad];
      const unsigned short* pl = &scr[1][arow * KSTS + 8 * quad];
      wAh[sl][0] = *reinterpret_cast<const f16x8*>(ph);
      wAh[sl][1] = *reinterpret_cast<const f16x8*>(ph + 32);
      wAl[sl][0] = *reinterpret_cast<const f16x8*>(pl);
      wAl[sl][1] = *reinterpret_cast<const f16x8*>(pl + 32);
    }
  }

  // per-lane C-row constants
  const int ic = 16 * wv + 4 * quad;
  const float* bi = (myL == 0) ? bih1 : (myL == 1) ? bih2 : bih3;
  const float* bh = (myL == 0) ? bhh1 : (myL == 1) ? bhh2 : bhh3;
  float wx0[4], wx1[4], bs[4];
#pragma unroll
  for (int r = 0; r < 4; ++r) {
    int i = ic + r;
    bool v = i < HD;
    bs[r] = v ? (bi[i] + bh[i]) : 0.0f;
    wx0[r] = (v && myL == 0) ? Wih1[i * 2 + 0] : 0.0f;
    wx1[r] = (v && myL == 0) ? Wih1[i * 2 + 1] : 0.0f;
  }

  const int selfBuf = myL;
  const int crossBuf = (myL > 0) ? myL - 1 : 0;
  const int ldsOff = l15 * KST + 8 * quad;
  constexpr float INV = 4.8828125e-4f;  // 2^-11

  // hoisted base pointers; per-slot offsets become literal immediates in steady state
  const unsigned short* sbase = hbuf + selfBuf * LAY_SH + ldsOff;
  const unsigned short* cbase = hbuf + crossBuf * LAY_SH + ldsOff;
  unsigned short* wbase = hbuf + myL * LAY_SH + l15 * KST + ic;

  f16x8 pfC0 = f16x8(0), pfC1 = f16x8(0);  // cross B-frags for the CURRENT iter

  __syncthreads();

  // one diagonal step: iter s computes h1_s, h2_{s-2}, h3_{s-4}
  auto step = [&](int s, int wr, int rd, bool act) {
    f16x8 bS0, bS1, pfN0, pfN1;
    if (act) {
      bS0 = *reinterpret_cast<const f16x8*>(sbase + rd * SLOT_SH);
      bS1 = *reinterpret_cast<const f16x8*>(sbase + rd * SLOT_SH + 32);
    }
    if (myL > 0) {  // prefetch cross frags for NEXT iter (slot rd; writers use wr != rd)
      pfN0 = *reinterpret_cast<const f16x8*>(cbase + rd * SLOT_SH);
      pfN1 = *reinterpret_cast<const f16x8*>(cbase + rd * SLOT_SH + 32);
    }
    if (act) {
      f32x4 c1, c2;
      if (myL == 0) {
        float2 xc = *reinterpret_cast<const float2*>(&xls[s][2 * l15]);
#pragma unroll
        for (int r = 0; r < 4; ++r) {
          c1[r] = bs[r] + wx0[r] * xc.x + wx1[r] * xc.y;
          c2[r] = 0.0f;
        }
        c1 = MFMA16(wAh[0][0], bS0, c1, 0, 0, 0);
        c2 = MFMA16(wAl[0][0], bS0, c2, 0, 0, 0);
        c1 = MFMA16(wAh[0][1], bS1, c1, 0, 0, 0);
        c2 = MFMA16(wAl[0][1], bS1, c2, 0, 0, 0);
      } else {
        // K-concat [cross | self]: single accumulator pair, 4-deep chains
#pragma unroll
        for (int r = 0; r < 4; ++r) { c1[r] = bs[r]; c2[r] = 0.0f; }
        c1 = MFMA16(wAh[0][0], pfC0, c1, 0, 0, 0);
        c2 = MFMA16(wAl[0][0], pfC0, c2, 0, 0, 0);
        c1 = MFMA16(wAh[0][1], pfC1, c1, 0, 0, 0);
        c2 = MFMA16(wAl[0][1], pfC1, c2, 0, 0, 0);
        c1 = MFMA16(wAh[1][0], bS0, c1, 0, 0, 0);
        c2 = MFMA16(wAl[1][0], bS0, c2, 0, 0, 0);
        c1 = MFMA16(wAh[1][1], bS1, c1, 0, 0, 0);
        c2 = MFMA16(wAl[1][1], bS1, c2, 0, 0, 0);
      }
      unsigned short ht[4];
#pragma unroll
      for (int r = 0; r < 4; ++r) ht[r] = f2h(fast_tanh(c1[r] + c2[r] * INV));
      unsigned int h01 = (unsigned int)ht[0] | ((unsigned int)ht[1] << 16);
      unsigned int h23 = (unsigned int)ht[2] | ((unsigned int)ht[3] << 16);
      *reinterpret_cast<uint2*>(wbase + wr * SLOT_SH) = make_uint2(h01, h23);
    }
    if (myL > 0) { pfC0 = pfN0; pfC1 = pfN1; }
    __syncthreads();
  };

  auto actOf = [&](int s) {
    return (myL == 0) ? (s < T_STEPS)
         : (myL == 1) ? (s >= 2 && s < T_STEPS + 2)
                      : (s >= 4);
  };

  // prologue s=0..3 (generic slots, act-gated)
  for (int s = 0; s < 4; ++s) step(s, s % 3, (s + 2) % 3, actOf(s));
  // steady s=4..255: all waves active; literal ring slots (84 x 3 steps)
  int sb = 4;
  for (int it = 0; it < 84; ++it, sb += 3) {
    step(sb + 0, 1, 0, true);   // s%3==1
    step(sb + 1, 2, 1, true);   // s%3==2
    step(sb + 2, 0, 2, true);   // s%3==0
  }
  // epilogue s=256..259
  for (int s = 256; s < 260; ++s) step(s, s % 3, (s + 2) % 3, actOf(s));

  // ---- fc epilogue: h3_255 written at s=259 -> slot 259%3 = 1 ----
  if (tid < BT * 2) {
    int b = tid >> 1, o = tid & 1;
    const unsigned short* h3 = hbuf + 1 * SLOT_SH + 2 * LAY_SH + b * KST;
    float acc = fcb[o];
    for (int i = 0; i < HD; ++i) acc += fcw[o * HD + i] * h2f(h3[i]);
    out[(size_t)(b0 + b) * 2 + o] = acc;
  }
}

}  // namespace

extern "C" void kernel_launch(void* const* d_in, const int* in_sizes, int n_in,
                              void* d_out, int out_size, void* d_ws, size_t ws_size,
                              hipStream_t stream) {
  const float* x = (const float*)d_in[0];
  const float* Wih1 = (const float*)d_in[1];
  const float* Whh1 = (const float*)d_in[2];
  const float* bih1 = (const float*)d_in[3];
  const float* bhh1 = (const float*)d_in[4];
  const float* Wih2 = (const float*)d_in[5];
  const float* Whh2 = (const float*)d_in[6];
  const float* bih2 = (const float*)d_in[7];
  const float* bhh2 = (const float*)d_in[8];
  const float* Wih3 = (const float*)d_in[9];
  const float* Whh3 = (const float*)d_in[10];
  const float* bih3 = (const float*)d_in[11];
  const float* bhh3 = (const float*)d_in[12];
  const float* fcw = (const float*)d_in[13];
  const float* fcb = (const float*)d_in[14];

  rnn3_kernel<<<4096 / BT, NTHR, 0, stream>>>(x, Wih1, Whh1, bih1, bhh1,
                                              Wih2, Whh2, bih2, bhh2,
                                              Wih3, Whh3, bih3, bhh3,
                                              fcw, fcb, (float*)d_out);
}